// Round 5
// baseline (1699.419 us; speedup 1.0000x reference)
//
#include <hip/hip_runtime.h>

#define DEVINL __device__ __forceinline__

typedef unsigned int  uint32;
typedef unsigned short u16;

typedef short bf16x8  __attribute__((ext_vector_type(8)));
typedef float f32x16  __attribute__((ext_vector_type(16)));
typedef float fx2     __attribute__((ext_vector_type(2)));

union U4H { uint4 u; bf16x8 h; };

// ---------------- path tables (15 paths, enumeration order of reference) ----
// idx: 0:(0,0,0,0,F) 1:(0,1,1,0,F) 2:(0,2,2,0,F) 3:(1,0,1,0,F) 4:(1,1,2,0,F)
//      5:(1,1,0,1,F) 6:(1,1,1,0,T) 7:(1,2,1,1,F) 8:(1,2,2,0,T) 9:(2,0,2,0,F)
//     10:(2,1,1,1,F) 11:(2,1,2,0,T) 12:(2,2,2,1,F) 13:(2,2,0,2,F) 14:(2,2,1,1,T)
constexpr int PL1c[15] = {0,0,0,1,1,1,1,1,1,2,2,2,2,2,2};
constexpr int PL2c[15] = {0,1,2,0,1,1,1,2,2,0,1,1,2,2,2};
constexpr int PLOc[15] = {0,1,2,1,2,0,1,1,2,2,1,2,2,0,1};
constexpr int PTc [15] = {1,1,1,1,1,3,2,3,2,1,3,2,3,9,6};
constexpr int PW3c[3]  = {1,3,9};
constexpr int LOFFc[3] = {0,32,128};

// groups g = (s_out = g&1, Lout = g>>1); combos (path, s1, s2)
constexpr int GCNT[6] = {6,6,12,12,12,12};
constexpr int GNT [6] = {1,1,3,3,9,9};
__device__ const int g_combo[6][12][3] = {
  {{0,0,0},{0,1,1},{5,0,0},{5,1,1},{13,0,0},{13,1,1},
   {0,0,0},{0,0,0},{0,0,0},{0,0,0},{0,0,0},{0,0,0}},
  {{0,0,1},{0,1,0},{5,0,1},{5,1,0},{13,0,1},{13,1,0},
   {0,0,0},{0,0,0},{0,0,0},{0,0,0},{0,0,0},{0,0,0}},
  {{1,0,0},{1,1,1},{3,0,0},{3,1,1},{7,0,0},{7,1,1},{10,0,0},{10,1,1},
   {6,0,1},{6,1,0},{14,0,1},{14,1,0}},
  {{1,0,1},{1,1,0},{3,0,1},{3,1,0},{7,0,1},{7,1,0},{10,0,1},{10,1,0},
   {6,0,0},{6,1,1},{14,0,0},{14,1,1}},
  {{2,0,0},{2,1,1},{4,0,0},{4,1,1},{9,0,0},{9,1,1},{12,0,0},{12,1,1},
   {8,0,1},{8,1,0},{11,0,1},{11,1,0}},
  {{2,0,1},{2,1,0},{4,0,1},{4,1,0},{9,0,1},{9,1,0},{12,0,1},{12,1,0},
   {8,0,0},{8,1,1},{11,0,0},{11,1,1}},
};

struct Terms { int iA[9]; int jB[9]; int sg[9]; };

DEVINL Terms make_terms(int path, int mo) {
  Terms t{};
  switch (path) {
    case 0:  t.iA[0]=0;  t.jB[0]=0;  t.sg[0]=1; break;
    case 1:  t.iA[0]=0;  t.jB[0]=mo; t.sg[0]=1; break;
    case 2:  t.iA[0]=0;  t.jB[0]=mo; t.sg[0]=1; break;
    case 3:  t.iA[0]=mo; t.jB[0]=0;  t.sg[0]=1; break;
    case 4:  t.iA[0]=mo/3; t.jB[0]=mo%3; t.sg[0]=1; break;
    case 5:  for (int v=0;v<3;++v){t.iA[v]=v; t.jB[v]=v; t.sg[v]=1;} break;
    case 6:  {int p=mo,u1=(p+1)%3,u2=(p+2)%3;
              t.iA[0]=u1; t.jB[0]=u2; t.sg[0]= 1;
              t.iA[1]=u2; t.jB[1]=u1; t.sg[1]=-1;} break;
    case 7:  {int x=mo; for(int u=0;u<3;++u){t.iA[u]=u; t.jB[u]=3*x+u; t.sg[u]=1;}} break;
    case 8:  {int x=mo/3,p=mo%3,u1=(p+1)%3,u2=(p+2)%3;
              t.iA[0]=u1; t.jB[0]=3*x+u2; t.sg[0]= 1;
              t.iA[1]=u2; t.jB[1]=3*x+u1; t.sg[1]=-1;} break;
    case 9:  t.iA[0]=mo; t.jB[0]=0; t.sg[0]=1; break;
    case 10: {int u=mo; for(int v=0;v<3;++v){t.iA[v]=3*u+v; t.jB[v]=v; t.sg[v]=1;}} break;
    case 11: {int u=mo/3,p=mo%3,v1=(p+1)%3,v2=(p+2)%3;
              t.iA[0]=3*u+v1; t.jB[0]=v2; t.sg[0]= 1;
              t.iA[1]=3*u+v2; t.jB[1]=v1; t.sg[1]=-1;} break;
    case 12: {int u=mo/3,x=mo%3; for(int v=0;v<3;++v){t.iA[v]=3*u+v; t.jB[v]=3*x+v; t.sg[v]=1;}} break;
    case 13: for (int w=0;w<9;++w){t.iA[w]=w; t.jB[w]=w; t.sg[w]=1;} break;
    case 14: {int p=mo,u1=(p+1)%3,u2=(p+2)%3;
              for(int v=0;v<3;++v){
                t.iA[2*v]  =3*u1+v; t.jB[2*v]  =3*u2+v; t.sg[2*v]  = 1;
                t.iA[2*v+1]=3*u2+v; t.jB[2*v+1]=3*u1+v; t.sg[2*v+1]=-1;}} break;
  }
  return t;
}

DEVINL u16 f2bf(float f) {            // RNE float->bf16
  uint32 u = __float_as_uint(f);
  u += 0x7fffu + ((u >> 16) & 1u);
  return (u16)(u >> 16);
}
DEVINL float bf2f(u16 h) { return __uint_as_float(((uint32)h) << 16); }

DEVINL void unpack8(uint4 r, fx2 out[4]) {   // sign applied on A scalar instead
  uint32 c[4] = {r.x, r.y, r.z, r.w};
#pragma unroll
  for (int q = 0; q < 4; ++q) {
    out[q].x = __uint_as_float(c[q] << 16);
    out[q].y = __uint_as_float(c[q] & 0xffff0000u);
  }
}

DEVINL bf16x8 packA(const fx2 p[4]) { // pack 8 f32 -> 8 bf16 (truncate)
  U4H r;
  r.u.x = __builtin_amdgcn_perm(__float_as_uint(p[0].y), __float_as_uint(p[0].x), 0x07060302u);
  r.u.y = __builtin_amdgcn_perm(__float_as_uint(p[1].y), __float_as_uint(p[1].x), 0x07060302u);
  r.u.z = __builtin_amdgcn_perm(__float_as_uint(p[2].y), __float_as_uint(p[2].x), 0x07060302u);
  r.u.w = __builtin_amdgcn_perm(__float_as_uint(p[3].y), __float_as_uint(p[3].x), 0x07060302u);
  return r.h;
}

DEVINL f32x16 mfma32(bf16x8 a, uint4 w, f32x16 c) {
  U4H x; x.u = w;
  return __builtin_amdgcn_mfma_f32_32x32x16_bf16(a, x.h, c, 0, 0, 0);
}

// ---------------- per-combo worker -----------------------------------------
// Wave split: bh = wv&1 (16-wide b half), a0 = (wv>>1)*8 (8 'a' channels).
// W fragments read straight from global Wb (pre-swizzled; each wave's slice is
// a disjoint 2048B-strided coalesced stream, L2-resident). No W barriers.
// T>3 paths split into <=3-term chunks via MFMA linearity in A.
template<int PATH, int NTC, int MOB>
DEVINL void run_combo(int s1, int s2, int n0,
                      const u16* __restrict__ x2t, const u16* x1l,
                      const uint4* __restrict__ wgl,
                      f32x16* acc, int lane, int wv)
{
  constexpr int L1v = PL1c[PATH];
  constexpr int L2v = PL2c[PATH];
  constexpr int T   = PTc[PATH];
  constexpr int P1v = PW3c[L1v];
  constexpr int NCH = (T + 2) / 3;
  const int bh   = wv & 1;
  const int a0   = (wv >> 1) * 8;
  const int nloc = lane & 31;
  const int oct  = lane >> 5;
  const u16* bb = x2t + (size_t)(n0 + nloc) * 832 + s2 * 416 + LOFFc[L2v]
                + bh * 16 + oct * 8;
  const u16* ab = x1l + nloc * 836 + s1 * 416 + LOFFc[L1v];
  const uint4* wbase = wgl + ((a0 * 2 + bh) << 6) + lane;  // +ia*128 per step
#pragma unroll
  for (int m = 0; m < NTC; ++m) {
    const Terms tm = make_terms(PATH, MOB + m);
#pragma unroll
    for (int tc = 0; tc < NCH; ++tc) {
      const int tlo = tc * 3;
      const int tn  = (T - tlo < 3) ? (T - tlo) : 3;
      fx2 b2[3][4];
#pragma unroll
      for (int u = 0; u < 3; ++u)
        if (u < tn) {
          uint4 rv = *(const uint4*)(bb + tm.jB[tlo + u] * 32);
          unpack8(rv, b2[u]);
        }
#pragma unroll
      for (int ia = 0; ia < 8; ++ia) {
        fx2 p[4];
#pragma unroll
        for (int u = 0; u < 3; ++u) {
          if (u < tn) {
            float av = bf2f(ab[(a0 + ia) * P1v + tm.iA[tlo + u]]);
            if (tm.sg[tlo + u] < 0) av = -av;
            fx2 a2; a2.x = av; a2.y = av;
            if (u == 0) {
#pragma unroll
              for (int q = 0; q < 4; ++q) p[q] = a2 * b2[0][q];
            } else {
#pragma unroll
              for (int q = 0; q < 4; ++q)
                p[q] = __builtin_elementwise_fma(a2, b2[u][q], p[q]);
            }
          }
        }
        uint4 wfr = wbase[ia * 128];           // global_load_dwordx4 (L2 hit)
        acc[m] = mfma32(packA(p), wfr, acc[m]);
      }
    }
  }
}

// one accumulator chunk: acc[NTC] (<=48 regs) over ALL combos of group G,
// then LDS-combine across waves and store this chunk's output columns.
template<int G, int MOB, int NTC>
DEVINL void process_chunk(int n0, const u16* __restrict__ x2t, const u16* x1l,
                          const uint4* __restrict__ Wb, float* red,
                          float* __restrict__ out, int tid, int lane, int wv)
{
  constexpr int lout  = G >> 1;
  constexpr int s_out = G & 1;
  constexpr int NTF   = GNT[G];
  __syncthreads();                       // prior chunk done reading red
  for (int i = tid; i < 1024 * NTC; i += 512) red[i] = 0.f;
  f32x16 acc[NTC];
#pragma unroll
  for (int t = 0; t < NTC; ++t)
#pragma unroll
    for (int e = 0; e < 16; ++e) acc[t][e] = 0.f;
  __syncthreads();                       // clear visible before atomics

#pragma unroll 1
  for (int ci = 0; ci < GCNT[G]; ++ci) {
    const int path = g_combo[G][ci][0];
    const int s1   = g_combo[G][ci][1];
    const int s2   = g_combo[G][ci][2];
    const int pc   = path * 4 + s1 * 2 + s2;
    const uint4* wgl = Wb + ((size_t)pc << 12);
#define RCASE(P) case P: if constexpr (PLOc[P] == lout) \
      run_combo<P, NTC, MOB>(s1, s2, n0, x2t, x1l, wgl, acc, lane, wv); break;
    switch (path) {
      RCASE(0) RCASE(1) RCASE(2) RCASE(3) RCASE(4) RCASE(5) RCASE(6) RCASE(7)
      RCASE(8) RCASE(9) RCASE(10) RCASE(11) RCASE(12) RCASE(13) RCASE(14)
    }
#undef RCASE
    __builtin_amdgcn_sched_barrier(0);   // no cross-combo code motion
  }
  // flush partial sums into LDS red
  const int col = lane & 31, oct = lane >> 5;
#pragma unroll
  for (int t = 0; t < NTC; ++t)
#pragma unroll
    for (int r = 0; r < 16; ++r) {
      int row = (r & 3) + 8 * (r >> 2) + 4 * oct;   // m74/m101 C/D layout
      atomicAdd(&red[((t * 32 + row) << 5) + col], acc[t][r]);
    }
  __syncthreads();                       // all atomics done
  // store this chunk's output columns: c = Z*NTF + (MOB + t)
  constexpr int obase = s_out * 416 + LOFFc[lout];
  for (int o = tid; o < 1024 * NTC; o += 512) {
    int t   = o % NTC;
    int zr  = o / NTC;                   // zr = row*32 + Z
    int Z   = zr & 31;
    int row = zr >> 5;
    out[(size_t)(n0 + row) * 832 + obase + Z * NTF + (MOB + t)]
        = red[((t * 32 + row) << 5) + Z];
  }
}

template<int G>
DEVINL void process_group(int n0, const u16* __restrict__ x2t, const u16* x1l,
                          const uint4* __restrict__ Wb, float* red,
                          float* __restrict__ out, int tid, int lane, int wv)
{
  if constexpr (GNT[G] == 9) {
    process_chunk<G, 0, 3>(n0, x2t, x1l, Wb, red, out, tid, lane, wv);
    process_chunk<G, 3, 3>(n0, x2t, x1l, Wb, red, out, tid, lane, wv);
    process_chunk<G, 6, 3>(n0, x2t, x1l, Wb, red, out, tid, lane, wv);
  } else {
    process_chunk<G, 0, GNT[G]>(n0, x2t, x1l, Wb, red, out, tid, lane, wv);
  }
}

// ---------------- main kernel ----------------------------------------------
// LDS 65.8KB -> 2 blocks/CU (4 waves/SIMD). Grid 512 = 256 row-tiles x 2
// balanced group-partitions {G4,G2,G1} / {G5,G3,G0} (1280 mfma/wave each,
// disjoint output columns). No W staging barriers (W from L2 global).
__global__ __launch_bounds__(512, 4)
void k_main(const float* __restrict__ x1, const u16* __restrict__ x2t,
            const uint4* __restrict__ Wb, float* __restrict__ out)
{
  __shared__ u16   x1l[32 * 836];      // 53,504 B (pad 836 -> 2-way, free)
  __shared__ float red[3072];          // 12,288 B cross-wave accumulator
  const int tid  = threadIdx.x;
  const int lane = tid & 63, wv = tid >> 6;
  const int tile = blockIdx.x >> 1;
  const int part = blockIdx.x & 1;     // pairs share x rows (L2 locality)
  const int n0   = tile * 32;

  { // stage x1 rows -> bf16 LDS (once)
    int rr = tid >> 4, c0 = tid & 15;
    const float* src = x1 + (size_t)(n0 + rr) * 832;
#pragma unroll 4
    for (int jj = 0; jj < 52; ++jj) {
      int colx = c0 + jj * 16;
      x1l[rr * 836 + colx] = f2bf(src[colx]);
    }
  }
  // barrier folded into first process_chunk's clear-sync

  if (part == 0) {
    process_group<4>(n0, x2t, x1l, Wb, red, out, tid, lane, wv);
    process_group<2>(n0, x2t, x1l, Wb, red, out, tid, lane, wv);
    process_group<1>(n0, x2t, x1l, Wb, red, out, tid, lane, wv);
  } else {
    process_group<5>(n0, x2t, x1l, Wb, red, out, tid, lane, wv);
    process_group<3>(n0, x2t, x1l, Wb, red, out, tid, lane, wv);
    process_group<0>(n0, x2t, x1l, Wb, red, out, tid, lane, wv);
  }
}

// ---------------- pre-kernels ----------------------------------------------
// W -> bf16, swizzled into exact B-fragment lane order:
//   Wb[pc][a][bh][l][j] = bf16( w[pc*32768 + Z*1024 + a*32 + b] ),
//   Z = l&31, b = bh*16 + ((l>>5)&1)*8 + j
__global__ void k_convw(const float* __restrict__ w, u16* __restrict__ Wb) {
  int o  = blockIdx.x * 1024 + threadIdx.x;      // 1,966,080 total
  int j  = o & 7;
  int l  = (o >> 3) & 63;
  int bh = (o >> 9) & 1;
  int a  = (o >> 10) & 31;
  int pc = o >> 15;
  int Z  = l & 31;
  int b  = bh * 16 + ((l >> 5) & 1) * 8 + j;
  float f = w[((size_t)pc << 15) + (size_t)Z * 1024 + a * 32 + b];
  Wb[o] = f2bf(f);
}

// x2 -> bf16, transposed within each (s,L) block to [j][b] so 8 consecutive
// b-channels are one 16B load: x2t[n*832 + s*416 + Loff + j*32 + b]
__global__ void k_convx2(const float* __restrict__ x2, u16* __restrict__ x2t) {
  int o = blockIdx.x * 1024 + threadIdx.x;       // 6,815,744 total
  int n = o / 832; int r = o - n * 832;
  int s = (r >= 416); int r2 = r - s * 416;
  int L = (r2 >= 32) + (r2 >= 128);
  int off = (L == 0) ? 0 : ((L == 1) ? 32 : 128);
  int c = r2 - off;
  int j = c >> 5, b = c & 31;
  int p3 = (L == 0) ? 1 : ((L == 1) ? 3 : 9);
  float f = x2[(size_t)n * 832 + s * 416 + off + b * p3 + j];
  x2t[o] = f2bf(f);
}

// ---------------- launch ----------------------------------------------------
extern "C" void kernel_launch(void* const* d_in, const int* in_sizes, int n_in,
                              void* d_out, int out_size, void* d_ws, size_t ws_size,
                              hipStream_t stream) {
  const float* x1 = (const float*)d_in[0];
  const float* x2 = (const float*)d_in[1];
  const float* w  = (const float*)d_in[2];
  float* out = (float*)d_out;
  // ws layout: [0, 3.93MB) swizzled bf16 W ; [4MB, 4MB+13.6MB) bf16 x2t
  u16* Wb  = (u16*)d_ws;
  u16* x2t = (u16*)((char*)d_ws + (4u << 20));
  (void)in_sizes; (void)n_in; (void)out_size; (void)ws_size;

  k_convw <<<1920, 1024, 0, stream>>>(w, Wb);    // 1920*1024 = 1,966,080
  k_convx2<<<6656, 1024, 0, stream>>>(x2, x2t);  // 6656*1024 = 6,815,744
  k_main  <<<512, 512, 0, stream>>>(x1, x2t, (const uint4*)Wb, out);
}

// Round 6
// 745.273 us; speedup vs baseline: 2.2803x; 2.2803x over previous
//
#include <hip/hip_runtime.h>

#define DEVINL __device__ __forceinline__

typedef unsigned int  uint32;
typedef unsigned short u16;

typedef short bf16x8  __attribute__((ext_vector_type(8)));
typedef float f32x16  __attribute__((ext_vector_type(16)));
typedef float fx2     __attribute__((ext_vector_type(2)));

union U4H { uint4 u; bf16x8 h; };

// ---------------- path tables (15 paths, enumeration order of reference) ----
// idx: 0:(0,0,0,0,F) 1:(0,1,1,0,F) 2:(0,2,2,0,F) 3:(1,0,1,0,F) 4:(1,1,2,0,F)
//      5:(1,1,0,1,F) 6:(1,1,1,0,T) 7:(1,2,1,1,F) 8:(1,2,2,0,T) 9:(2,0,2,0,F)
//     10:(2,1,1,1,F) 11:(2,1,2,0,T) 12:(2,2,2,1,F) 13:(2,2,0,2,F) 14:(2,2,1,1,T)
constexpr int PL1c[15] = {0,0,0,1,1,1,1,1,1,2,2,2,2,2,2};
constexpr int PL2c[15] = {0,1,2,0,1,1,1,2,2,0,1,1,2,2,2};
constexpr int PLOc[15] = {0,1,2,1,2,0,1,1,2,2,1,2,2,0,1};
constexpr int PTc [15] = {1,1,1,1,1,3,2,3,2,1,3,2,3,9,6};
constexpr int PW3c[3]  = {1,3,9};
constexpr int LOFFc[3] = {0,32,128};

// groups g = (s_out = g&1, Lout = g>>1); combos (path, s1, s2)
constexpr int GCNT[6] = {6,6,12,12,12,12};
constexpr int GNT [6] = {1,1,3,3,9,9};
__device__ const int g_combo[6][12][3] = {
  {{0,0,0},{0,1,1},{5,0,0},{5,1,1},{13,0,0},{13,1,1},
   {0,0,0},{0,0,0},{0,0,0},{0,0,0},{0,0,0},{0,0,0}},
  {{0,0,1},{0,1,0},{5,0,1},{5,1,0},{13,0,1},{13,1,0},
   {0,0,0},{0,0,0},{0,0,0},{0,0,0},{0,0,0},{0,0,0}},
  {{1,0,0},{1,1,1},{3,0,0},{3,1,1},{7,0,0},{7,1,1},{10,0,0},{10,1,1},
   {6,0,1},{6,1,0},{14,0,1},{14,1,0}},
  {{1,0,1},{1,1,0},{3,0,1},{3,1,0},{7,0,1},{7,1,0},{10,0,1},{10,1,0},
   {6,0,0},{6,1,1},{14,0,0},{14,1,1}},
  {{2,0,0},{2,1,1},{4,0,0},{4,1,1},{9,0,0},{9,1,1},{12,0,0},{12,1,1},
   {8,0,1},{8,1,0},{11,0,1},{11,1,0}},
  {{2,0,1},{2,1,0},{4,0,1},{4,1,0},{9,0,1},{9,1,0},{12,0,1},{12,1,0},
   {8,0,0},{8,1,1},{11,0,0},{11,1,1}},
};

struct Terms { int iA[9]; int jB[9]; int sg[9]; };

DEVINL Terms make_terms(int path, int mo) {
  Terms t{};
  switch (path) {
    case 0:  t.iA[0]=0;  t.jB[0]=0;  t.sg[0]=1; break;
    case 1:  t.iA[0]=0;  t.jB[0]=mo; t.sg[0]=1; break;
    case 2:  t.iA[0]=0;  t.jB[0]=mo; t.sg[0]=1; break;
    case 3:  t.iA[0]=mo; t.jB[0]=0;  t.sg[0]=1; break;
    case 4:  t.iA[0]=mo/3; t.jB[0]=mo%3; t.sg[0]=1; break;
    case 5:  for (int v=0;v<3;++v){t.iA[v]=v; t.jB[v]=v; t.sg[v]=1;} break;
    case 6:  {int p=mo,u1=(p+1)%3,u2=(p+2)%3;
              t.iA[0]=u1; t.jB[0]=u2; t.sg[0]= 1;
              t.iA[1]=u2; t.jB[1]=u1; t.sg[1]=-1;} break;
    case 7:  {int x=mo; for(int u=0;u<3;++u){t.iA[u]=u; t.jB[u]=3*x+u; t.sg[u]=1;}} break;
    case 8:  {int x=mo/3,p=mo%3,u1=(p+1)%3,u2=(p+2)%3;
              t.iA[0]=u1; t.jB[0]=3*x+u2; t.sg[0]= 1;
              t.iA[1]=u2; t.jB[1]=3*x+u1; t.sg[1]=-1;} break;
    case 9:  t.iA[0]=mo; t.jB[0]=0; t.sg[0]=1; break;
    case 10: {int u=mo; for(int v=0;v<3;++v){t.iA[v]=3*u+v; t.jB[v]=v; t.sg[v]=1;}} break;
    case 11: {int u=mo/3,p=mo%3,v1=(p+1)%3,v2=(p+2)%3;
              t.iA[0]=3*u+v1; t.jB[0]=v2; t.sg[0]= 1;
              t.iA[1]=3*u+v2; t.jB[1]=v1; t.sg[1]=-1;} break;
    case 12: {int u=mo/3,x=mo%3; for(int v=0;v<3;++v){t.iA[v]=3*u+v; t.jB[v]=3*x+v; t.sg[v]=1;}} break;
    case 13: for (int w=0;w<9;++w){t.iA[w]=w; t.jB[w]=w; t.sg[w]=1;} break;
    case 14: {int p=mo,u1=(p+1)%3,u2=(p+2)%3;
              for(int v=0;v<3;++v){
                t.iA[2*v]  =3*u1+v; t.jB[2*v]  =3*u2+v; t.sg[2*v]  = 1;
                t.iA[2*v+1]=3*u2+v; t.jB[2*v+1]=3*u1+v; t.sg[2*v+1]=-1;}} break;
  }
  return t;
}

DEVINL u16 f2bf(float f) {            // RNE float->bf16
  uint32 u = __float_as_uint(f);
  u += 0x7fffu + ((u >> 16) & 1u);
  return (u16)(u >> 16);
}
DEVINL float bf2f(u16 h) { return __uint_as_float(((uint32)h) << 16); }

DEVINL void unpack8(uint4 r, fx2 out[4]) {   // sign applied on A scalar instead
  uint32 c[4] = {r.x, r.y, r.z, r.w};
#pragma unroll
  for (int q = 0; q < 4; ++q) {
    out[q].x = __uint_as_float(c[q] << 16);
    out[q].y = __uint_as_float(c[q] & 0xffff0000u);
  }
}

DEVINL bf16x8 packA(const fx2 p[4]) { // pack 8 f32 -> 8 bf16 (truncate)
  U4H r;
  r.u.x = __builtin_amdgcn_perm(__float_as_uint(p[0].y), __float_as_uint(p[0].x), 0x07060302u);
  r.u.y = __builtin_amdgcn_perm(__float_as_uint(p[1].y), __float_as_uint(p[1].x), 0x07060302u);
  r.u.z = __builtin_amdgcn_perm(__float_as_uint(p[2].y), __float_as_uint(p[2].x), 0x07060302u);
  r.u.w = __builtin_amdgcn_perm(__float_as_uint(p[3].y), __float_as_uint(p[3].x), 0x07060302u);
  return r.h;
}

DEVINL f32x16 mfma32(bf16x8 a, uint4 w, f32x16 c) {
  U4H x; x.u = w;
  return __builtin_amdgcn_mfma_f32_32x32x16_bf16(a, x.h, c, 0, 0, 0);
}

// ---------------- per-combo worker -----------------------------------------
// Wave split: bh = wv&1 (16-wide b half), a0 = (wv>>1)*8 (8 'a' channels).
// W fragments preloaded global->VGPR at combo start (disjoint coalesced
// per-wave slices of pre-swizzled L2-resident Wb; 8 loads in flight).
// T>3 paths split into <=3-term chunks via MFMA linearity in A.
template<int PATH, int NTC, int MOB>
DEVINL void run_combo(int s1, int s2, int n0,
                      const u16* __restrict__ x2t, const u16* x1l,
                      const uint4* __restrict__ wgl,
                      f32x16* acc, int lane, int wv)
{
  constexpr int L1v = PL1c[PATH];
  constexpr int L2v = PL2c[PATH];
  constexpr int T   = PTc[PATH];
  constexpr int P1v = PW3c[L1v];
  constexpr int NCH = (T + 2) / 3;
  const int bh   = wv & 1;
  const int a0   = (wv >> 1) * 8;
  const int nloc = lane & 31;
  const int oct  = lane >> 5;
  const u16* bb = x2t + (size_t)(n0 + nloc) * 832 + s2 * 416 + LOFFc[L2v]
                + bh * 16 + oct * 8;
  const u16* ab = x1l + nloc * 836 + s1 * 416 + LOFFc[L1v];
  const uint4* wbase = wgl + ((a0 * 2 + bh) << 6) + lane;
  uint4 wf[8];                           // resident for the whole combo
#pragma unroll
  for (int ia = 0; ia < 8; ++ia)
    wf[ia] = wbase[ia * 128];            // global_load_dwordx4, L2 hit
#pragma unroll
  for (int m = 0; m < NTC; ++m) {
    const Terms tm = make_terms(PATH, MOB + m);
#pragma unroll
    for (int tc = 0; tc < NCH; ++tc) {
      const int tlo = tc * 3;
      const int tn  = (T - tlo < 3) ? (T - tlo) : 3;
      fx2 b2[3][4];
#pragma unroll
      for (int u = 0; u < 3; ++u)
        if (u < tn) {
          uint4 rv = *(const uint4*)(bb + tm.jB[tlo + u] * 32);
          unpack8(rv, b2[u]);
        }
#pragma unroll
      for (int ia = 0; ia < 8; ++ia) {
        fx2 p[4];
#pragma unroll
        for (int u = 0; u < 3; ++u) {
          if (u < tn) {
            float av = bf2f(ab[(a0 + ia) * P1v + tm.iA[tlo + u]]);
            if (tm.sg[tlo + u] < 0) av = -av;
            fx2 a2; a2.x = av; a2.y = av;
            if (u == 0) {
#pragma unroll
              for (int q = 0; q < 4; ++q) p[q] = a2 * b2[0][q];
            } else {
#pragma unroll
              for (int q = 0; q < 4; ++q)
                p[q] = __builtin_elementwise_fma(a2, b2[u][q], p[q]);
            }
          }
        }
        acc[m] = mfma32(packA(p), wf[ia], acc[m]);
      }
    }
  }
}

// one accumulator chunk: acc[NTC] (<=48 regs) over ALL combos of group G,
// then LDS-combine across waves and store this chunk's output columns.
// NO barriers inside the combo loop (no W staging).
template<int G, int MOB, int NTC>
DEVINL void process_chunk(int n0, const u16* __restrict__ x2t, const u16* x1l,
                          const uint4* __restrict__ Wb, float* red,
                          float* __restrict__ out, int tid, int lane, int wv)
{
  constexpr int lout  = G >> 1;
  constexpr int s_out = G & 1;
  constexpr int NTF   = GNT[G];
  __syncthreads();                       // prior chunk done reading red
  for (int i = tid; i < 1024 * NTC; i += 512) red[i] = 0.f;
  f32x16 acc[NTC];
#pragma unroll
  for (int t = 0; t < NTC; ++t)
#pragma unroll
    for (int e = 0; e < 16; ++e) acc[t][e] = 0.f;
  __syncthreads();                       // clear visible before atomics

#pragma unroll 1
  for (int ci = 0; ci < GCNT[G]; ++ci) {
    const int path = g_combo[G][ci][0];
    const int s1   = g_combo[G][ci][1];
    const int s2   = g_combo[G][ci][2];
    const int pc   = path * 4 + s1 * 2 + s2;
    const uint4* wgl = Wb + ((size_t)pc << 12);
#define RCASE(P) case P: if constexpr (PLOc[P] == lout) \
      run_combo<P, NTC, MOB>(s1, s2, n0, x2t, x1l, wgl, acc, lane, wv); break;
    switch (path) {
      RCASE(0) RCASE(1) RCASE(2) RCASE(3) RCASE(4) RCASE(5) RCASE(6) RCASE(7)
      RCASE(8) RCASE(9) RCASE(10) RCASE(11) RCASE(12) RCASE(13) RCASE(14)
    }
#undef RCASE
    __builtin_amdgcn_sched_barrier(0);   // no cross-combo code motion
  }
  // flush partial sums into LDS red
  const int col = lane & 31, oct = lane >> 5;
#pragma unroll
  for (int t = 0; t < NTC; ++t)
#pragma unroll
    for (int r = 0; r < 16; ++r) {
      int row = (r & 3) + 8 * (r >> 2) + 4 * oct;   // m74/m101 C/D layout
      atomicAdd(&red[((t * 32 + row) << 5) + col], acc[t][r]);
    }
  __syncthreads();                       // all atomics done
  // store this chunk's output columns: c = Z*NTF + (MOB + t)
  constexpr int obase = s_out * 416 + LOFFc[lout];
  for (int o = tid; o < 1024 * NTC; o += 512) {
    int t   = o % NTC;
    int zr  = o / NTC;                   // zr = row*32 + Z
    int Z   = zr & 31;
    int row = zr >> 5;
    out[(size_t)(n0 + row) * 832 + obase + Z * NTF + (MOB + t)]
        = red[((t * 32 + row) << 5) + Z];
  }
}

template<int G>
DEVINL void process_group(int n0, const u16* __restrict__ x2t, const u16* x1l,
                          const uint4* __restrict__ Wb, float* red,
                          float* __restrict__ out, int tid, int lane, int wv)
{
  if constexpr (GNT[G] == 9) {
    process_chunk<G, 0, 3>(n0, x2t, x1l, Wb, red, out, tid, lane, wv);
    process_chunk<G, 3, 3>(n0, x2t, x1l, Wb, red, out, tid, lane, wv);
    process_chunk<G, 6, 3>(n0, x2t, x1l, Wb, red, out, tid, lane, wv);
  } else {
    process_chunk<G, 0, GNT[G]>(n0, x2t, x1l, Wb, red, out, tid, lane, wv);
  }
}

// ---------------- main kernel ----------------------------------------------
// __launch_bounds__(512,1): 1 block/CU = 2 waves/SIMD = ~256 regs/wave
// (per-SIMD pool ~512; R1-R4 compiled at (512,2)->128 regs -> spills; R5 at
// (512,4)->64 regs -> spill explosion. The 2nd arg is BLOCKS/CU.)
// Worst-case live set: acc 48 + wf 32 + b2 24 + p/pack 12 + addr ~40 ~ 156.
__global__ __launch_bounds__(512, 1)
void k_main(const float* __restrict__ x1, const u16* __restrict__ x2t,
            const uint4* __restrict__ Wb, float* __restrict__ out)
{
  __shared__ u16   x1l[32 * 836];      // 53,504 B (pad 836 -> 2-way, free)
  __shared__ float red[3072];          // 12,288 B cross-wave accumulator
  const int tid  = threadIdx.x;
  const int lane = tid & 63, wv = tid >> 6;
  const int n0   = blockIdx.x * 32;

  { // stage x1 rows -> bf16 LDS (once)
    int rr = tid >> 4, c0 = tid & 15;
    const float* src = x1 + (size_t)(n0 + rr) * 832;
#pragma unroll 4
    for (int jj = 0; jj < 52; ++jj) {
      int colx = c0 + jj * 16;
      x1l[rr * 836 + colx] = f2bf(src[colx]);
    }
  }
  // barrier folded into first process_chunk's clear-sync

  process_group<0>(n0, x2t, x1l, Wb, red, out, tid, lane, wv);
  process_group<1>(n0, x2t, x1l, Wb, red, out, tid, lane, wv);
  process_group<2>(n0, x2t, x1l, Wb, red, out, tid, lane, wv);
  process_group<3>(n0, x2t, x1l, Wb, red, out, tid, lane, wv);
  process_group<4>(n0, x2t, x1l, Wb, red, out, tid, lane, wv);
  process_group<5>(n0, x2t, x1l, Wb, red, out, tid, lane, wv);
}

// ---------------- pre-kernels ----------------------------------------------
// W -> bf16, swizzled into exact B-fragment lane order:
//   Wb[pc][a][bh][l][j] = bf16( w[pc*32768 + Z*1024 + a*32 + b] ),
//   Z = l&31, b = bh*16 + ((l>>5)&1)*8 + j
__global__ void k_convw(const float* __restrict__ w, u16* __restrict__ Wb) {
  int o  = blockIdx.x * 1024 + threadIdx.x;      // 1,966,080 total
  int j  = o & 7;
  int l  = (o >> 3) & 63;
  int bh = (o >> 9) & 1;
  int a  = (o >> 10) & 31;
  int pc = o >> 15;
  int Z  = l & 31;
  int b  = bh * 16 + ((l >> 5) & 1) * 8 + j;
  float f = w[((size_t)pc << 15) + (size_t)Z * 1024 + a * 32 + b];
  Wb[o] = f2bf(f);
}

// x2 -> bf16, transposed within each (s,L) block to [j][b] so 8 consecutive
// b-channels are one 16B load: x2t[n*832 + s*416 + Loff + j*32 + b]
__global__ void k_convx2(const float* __restrict__ x2, u16* __restrict__ x2t) {
  int o = blockIdx.x * 1024 + threadIdx.x;       // 6,815,744 total
  int n = o / 832; int r = o - n * 832;
  int s = (r >= 416); int r2 = r - s * 416;
  int L = (r2 >= 32) + (r2 >= 128);
  int off = (L == 0) ? 0 : ((L == 1) ? 32 : 128);
  int c = r2 - off;
  int j = c >> 5, b = c & 31;
  int p3 = (L == 0) ? 1 : ((L == 1) ? 3 : 9);
  float f = x2[(size_t)n * 832 + s * 416 + off + b * p3 + j];
  x2t[o] = f2bf(f);
}

// ---------------- launch ----------------------------------------------------
extern "C" void kernel_launch(void* const* d_in, const int* in_sizes, int n_in,
                              void* d_out, int out_size, void* d_ws, size_t ws_size,
                              hipStream_t stream) {
  const float* x1 = (const float*)d_in[0];
  const float* x2 = (const float*)d_in[1];
  const float* w  = (const float*)d_in[2];
  float* out = (float*)d_out;
  // ws layout: [0, 3.93MB) swizzled bf16 W ; [4MB, 4MB+13.6MB) bf16 x2t
  u16* Wb  = (u16*)d_ws;
  u16* x2t = (u16*)((char*)d_ws + (4u << 20));
  (void)in_sizes; (void)n_in; (void)out_size; (void)ws_size;

  k_convw <<<1920, 1024, 0, stream>>>(w, Wb);    // 1920*1024 = 1,966,080
  k_convx2<<<6656, 1024, 0, stream>>>(x2, x2t);  // 6656*1024 = 6,815,744
  k_main  <<<256, 512, 0, stream>>>(x1, x2t, (const uint4*)Wb, out);
}